// Round 5
// baseline (48885.855 us; speedup 1.0000x reference)
//
#include <hip/hip_runtime.h>
#include <cstdint>
#include <cstddef>

#define T_STEPS 1024
#define S_DIM   1024
#define A_DIM   64
#define D_DIM   2048
#define H_DIM   2048
#define NWG     256
#define NTHR    1024   // 16 waves per WG, 1 WG per CU

typedef unsigned short ushort_t;

__device__ __forceinline__ float eluf(float v)      { return v > 0.f ? v : expm1f(v); }
__device__ __forceinline__ float softplusf(float v) { return v > 20.f ? v : log1pf(expf(v)); }
__device__ __forceinline__ float sigmoidf_(float v) { return 1.f / (1.f + expf(-v)); }

__device__ __forceinline__ float wave_reduce(float v) {
  #pragma unroll
  for (int off = 32; off > 0; off >>= 1) v += __shfl_xor(v, off, 64);
  return v;
}

// unpack a u32 holding two bf16 (e0 = low half, e1 = high half)
__device__ __forceinline__ float2 bf2(unsigned u) {
  float2 r;
  r.x = __uint_as_float(u << 16);
  r.y = __uint_as_float(u & 0xffff0000u);
  return r;
}
__device__ __forceinline__ ushort_t f2bf_rne(float f) {
  unsigned u = __float_as_uint(f);
  u += 0x7fffu + ((u >> 16) & 1u);
  return (ushort_t)(u >> 16);
}

// ---- coherent (cross-XCD) accesses: bypass L1/L2, hit the coherence point.
__device__ __forceinline__ float4 ld_coh_f4(const float* p) {
  float4 v;
  asm volatile("global_load_dwordx4 %0, %1, off sc0 sc1\n\ts_waitcnt vmcnt(0)"
               : "=v"(v) : "v"(p) : "memory");
  return v;
}
// store + completion fence (so grid_bar needn't drain vmcnt)
__device__ __forceinline__ void st_coh_f1_fence(float* p, float v) {
  asm volatile("global_store_dword %0, %1, off sc0 sc1\n\ts_waitcnt vmcnt(0)"
               :: "v"(p), "v"(v) : "memory");
}

__global__ void init_flags(unsigned* f) { f[threadIdx.x] = 0u; }

// Packed-flag grid barrier: 256 contiguous u32; lane l polls flags[4l..4l+3]
// with ONE dwordx4 round trip.
__device__ __forceinline__ void grid_bar(unsigned* flags, int bid, unsigned gen, int tid) {
  __syncthreads();   // all epilogue stores already vmcnt-fenced per-thread
  if (tid == 0)
    asm volatile("global_store_dword %0, %1, off sc0 sc1"
                 :: "v"(flags + bid), "v"(gen) : "memory");
  if (tid < 64) {
    const unsigned* p = flags + tid * 4;
    bool done;
    do {
      uint4 f;
      asm volatile("global_load_dwordx4 %0, %1, off sc0 sc1\n\ts_waitcnt vmcnt(0)"
                   : "=v"(f) : "v"(p) : "memory");
      done = (f.x >= gen) && (f.y >= gen) && (f.z >= gen) && (f.w >= gen);
    } while (!__all(done));
  }
  __syncthreads();
}

// fp32 -> bf16 pack with per-512-chunk column swizzle:
// dst pos (within row): chunk*512 + l*8 + p*2 + e  <-  src k: chunk*512 + p*128 + l*2 + e
__global__ __launch_bounds__(256) void pack_swz(
    const float* __restrict__ src, unsigned* __restrict__ dst,
    int src_ld, int lc /*log2 cols*/, size_t total2 /*u32 count*/)
{
  for (size_t u = (size_t)blockIdx.x * 256 + threadIdx.x; u < total2;
       u += (size_t)gridDim.x * 256) {
    const size_t pos = u * 2;
    const size_t row = pos >> lc;
    const int pcol  = (int)(pos & (((size_t)1 << lc) - 1));
    const int chunk = pcol >> 9;
    const int off   = pcol & 511;
    const int l     = off >> 3;
    const int p     = (off >> 1) & 3;
    const float2 v  = *(const float2*)(src + row * src_ld + chunk * 512 + p * 128 + l * 2);
    dst[u] = (unsigned)f2bf_rne(v.x) | ((unsigned)f2bf_rne(v.y) << 16);
  }
}

// dot of one swizzled 512-chunk (uint4 = 8 bf16) against LDS chunk
__device__ __forceinline__ float chunk_dot(const uint4 w, const float* vchunk, int lane) {
  float acc = 0.f; float2 p, a;
  a = *(const float2*)(vchunk + lane * 2 +   0); p = bf2(w.x); acc += p.x*a.x + p.y*a.y;
  a = *(const float2*)(vchunk + lane * 2 + 128); p = bf2(w.y); acc += p.x*a.x + p.y*a.y;
  a = *(const float2*)(vchunk + lane * 2 + 256); p = bf2(w.z); acc += p.x*a.x + p.y*a.y;
  a = *(const float2*)(vchunk + lane * 2 + 384); p = bf2(w.w); acc += p.x*a.x + p.y*a.y;
  return acc;
}

__global__ __launch_bounds__(NTHR, 4) void rssm_seq(
    const float* __restrict__ pre_act, const float* __restrict__ pre_e,
    float* __restrict__ xbuf, float* __restrict__ qbuf, unsigned* __restrict__ flags,
    const ushort_t* __restrict__ wps,
    const ushort_t* __restrict__ wih, const ushort_t* __restrict__ whh,
    const float* __restrict__ gru_b, const float* __restrict__ gru_bn,
    const ushort_t* __restrict__ wqe, const ushort_t* __restrict__ wqd,
    const float* __restrict__ q_dec_b, const float* __restrict__ noise,
    float* __restrict__ stoch_out, float* __restrict__ det_out,
    float* __restrict__ qmu_out, float* __restrict__ qstd_out)
{
  __shared__ float sp[1024];      // stoch_prev
  __shared__ float xs[2048];      // x vector
  __shared__ float ds[2048];      // det_prev; becomes det_t in stage3, persists to next step
  __shared__ float qs[2048];      // q vector
  __shared__ float part1[8][2];
  __shared__ float partg[8][6];
  __shared__ float part3[8][2];
  __shared__ float part4[8][2];

  const int tid  = threadIdx.x;
  const int wv   = tid >> 6;          // 0..15
  const int lane = tid & 63;
  const int bid  = blockIdx.x;
  const int r0   = bid * 8;           // 8 rows of 2048 per WG
  unsigned gen = 0;

  // ---------------- resident weights: loaded ONCE, live across the whole scan ----------------
  uint4 w1;       // stage1: row r0+(wv&7), k-chunk (wv>>3) of 1024
  {
    const int row = wv & 7, half = wv >> 3;
    const uint4* wr = (const uint4*)(wps + (size_t)(r0 + row) * 1024);
    w1 = wr[half * 64 + lane];
  }
  uint4 w2[12];   // stage2: 3 gate rows (ih for wv<8, hh for wv>=8) of row r0+(wv&7), K=2048
  {
    const int row = wv & 7;
    const ushort_t* wbase = (wv < 8) ? wih : whh;
    const size_t i = (size_t)(r0 + row);
    #pragma unroll
    for (int g = 0; g < 3; ++g) {
      const uint4* wr = (const uint4*)(wbase + (i + (size_t)g * 2048) * 2048);
      #pragma unroll
      for (int j = 0; j < 4; ++j) w2[g * 4 + j] = wr[j * 64 + lane];
    }
  }
  uint4 w3[2];    // stage3: row r0+(wv&7), k-half (wv>>3) of 2048
  {
    const int row = wv & 7, half = wv >> 3;
    const uint4* wr = (const uint4*)(wqe + (size_t)(r0 + row) * 2048);
    w3[0] = wr[(2 * half)     * 64 + lane];
    w3[1] = wr[(2 * half + 1) * 64 + lane];
  }
  uint4 w4[2];    // stage4: dot (wv>>1), k-half (wv&1)
  {
    const int dot = wv >> 1, half = wv & 1;
    const int jg = bid * 4 + (dot & 3), sel = dot >> 2;
    const uint4* wr = (const uint4*)(wqd + (size_t)(jg + sel * 1024) * 2048);
    w4[0] = wr[(2 * half)     * 64 + lane];
    w4[1] = wr[(2 * half + 1) * 64 + lane];
  }

  // per-row constants, resident
  float gb_r = 0.f, gb_z = 0.f, gb_n = 0.f, gbn = 0.f, qdb_m = 0.f, qdb_s = 0.f;
  if (tid < 8) {
    gb_r = gru_b[r0 + tid];
    gb_z = gru_b[r0 + tid + 2048];
    gb_n = gru_b[r0 + tid + 4096];
    gbn  = gru_bn[r0 + tid];
  }
  if (tid < 4) {
    qdb_m = q_dec_b[bid * 4 + tid];
    qdb_s = q_dec_b[bid * 4 + tid + 1024];
  }

  // det_prev = 0 for t=0 (ds persists across iterations thereafter)
  if (tid < 512) ((float4*)ds)[tid] = float4{0.f, 0.f, 0.f, 0.f};

  for (int t = 0; t < T_STEPS; ++t) {
    // issue this step's small uniform loads early (consumed in epilogues)
    float pa = 0.f, pe = 0.f, nz = 0.f;
    if (tid < 8) {
      pa = pre_act[(size_t)t * D_DIM + r0 + tid];
      pe = pre_e  [(size_t)t * H_DIM + r0 + tid];
    }
    if (tid < 4) nz = noise[(size_t)t * S_DIM + bid * 4 + tid];

    // stage stoch_prev
    if (tid < 256) {
      ((float4*)sp)[tid] = (t > 0)
        ? ld_coh_f4(stoch_out + (size_t)(t - 1) * S_DIM + tid * 4)
        : float4{0.f, 0.f, 0.f, 0.f};
    }
    __syncthreads();

    // ================= stage 1: x = elu(Wps @ stoch_prev + pre_act[t]) =================
    {
      const int row = wv & 7, half = wv >> 3;
      float acc = wave_reduce(chunk_dot(w1, sp + half * 512, lane));
      if (lane == 0) part1[row][half] = acc;
    }
    __syncthreads();
    if (tid < 8)
      st_coh_f1_fence(xbuf + r0 + tid, eluf(part1[tid][0] + part1[tid][1] + pa));
    grid_bar(flags, bid, ++gen, tid);

    // ================= stage 2: GRU -> det[t] =================
    if (tid < 512) ((float4*)xs)[tid] = ld_coh_f4(xbuf + tid * 4);
    __syncthreads();
    {
      const float* vec = (wv < 8) ? xs : ds;
      float a0 = 0.f, a1 = 0.f, a2 = 0.f;
      #pragma unroll
      for (int j = 0; j < 4; ++j) {
        const float* b = vec + j * 512 + lane * 2;
        const float2 v0 = *(const float2*)(b);
        const float2 v1 = *(const float2*)(b + 128);
        const float2 v2 = *(const float2*)(b + 256);
        const float2 v3 = *(const float2*)(b + 384);
        float2 p; uint4 w;
        w = w2[j];
        p = bf2(w.x); a0 += p.x*v0.x + p.y*v0.y;
        p = bf2(w.y); a0 += p.x*v1.x + p.y*v1.y;
        p = bf2(w.z); a0 += p.x*v2.x + p.y*v2.y;
        p = bf2(w.w); a0 += p.x*v3.x + p.y*v3.y;
        w = w2[4 + j];
        p = bf2(w.x); a1 += p.x*v0.x + p.y*v0.y;
        p = bf2(w.y); a1 += p.x*v1.x + p.y*v1.y;
        p = bf2(w.z); a1 += p.x*v2.x + p.y*v2.y;
        p = bf2(w.w); a1 += p.x*v3.x + p.y*v3.y;
        w = w2[8 + j];
        p = bf2(w.x); a2 += p.x*v0.x + p.y*v0.y;
        p = bf2(w.y); a2 += p.x*v1.x + p.y*v1.y;
        p = bf2(w.z); a2 += p.x*v2.x + p.y*v2.y;
        p = bf2(w.w); a2 += p.x*v3.x + p.y*v3.y;
      }
      a0 = wave_reduce(a0); a1 = wave_reduce(a1); a2 = wave_reduce(a2);
      if (lane == 0) {
        const int row = wv & 7;
        if (wv < 8) { partg[row][0] = a0; partg[row][1] = a1; partg[row][2] = a2; }
        else        { partg[row][3] = a0; partg[row][4] = a1; partg[row][5] = a2; }
      }
    }
    __syncthreads();
    if (tid < 8) {
      const float r_ = sigmoidf_(partg[tid][0] + gb_r + partg[tid][3]);
      const float z_ = sigmoidf_(partg[tid][1] + gb_z + partg[tid][4]);
      const float n_ = tanhf(partg[tid][2] + gb_n + r_ * (partg[tid][5] + gbn));
      st_coh_f1_fence(det_out + (size_t)t * D_DIM + r0 + tid, n_ + z_ * (ds[r0 + tid] - n_));
    }
    grid_bar(flags, bid, ++gen, tid);

    // ================= stage 3: q = elu(Wqe @ det_t + pre_e[t]) =================
    if (tid < 512) ((float4*)ds)[tid] = ld_coh_f4(det_out + (size_t)t * D_DIM + tid * 4);
    __syncthreads();
    {
      const int row = wv & 7, half = wv >> 3;
      float acc = chunk_dot(w3[0], ds + (2 * half) * 512, lane)
                + chunk_dot(w3[1], ds + (2 * half + 1) * 512, lane);
      acc = wave_reduce(acc);
      if (lane == 0) part3[row][half] = acc;
    }
    __syncthreads();
    if (tid < 8)
      st_coh_f1_fence(qbuf + r0 + tid, eluf(part3[tid][0] + part3[tid][1] + pe));
    grid_bar(flags, bid, ++gen, tid);

    // ================= stage 4: posterior head + sample =================
    if (tid < 512) ((float4*)qs)[tid] = ld_coh_f4(qbuf + tid * 4);
    __syncthreads();
    {
      const int dot = wv >> 1, half = wv & 1;
      float acc = chunk_dot(w4[0], qs + (2 * half) * 512, lane)
                + chunk_dot(w4[1], qs + (2 * half + 1) * 512, lane);
      acc = wave_reduce(acc);
      if (lane == 0) part4[dot][half] = acc;
    }
    __syncthreads();
    if (tid < 4) {
      const int j = bid * 4 + tid;
      const float qm  = part4[tid][0] + part4[tid][1] + qdb_m;
      const float qsd = softplusf(part4[tid + 4][0] + part4[tid + 4][1] + qdb_s) + 0.1f;
      qmu_out [(size_t)t * S_DIM + j] = qm;
      qstd_out[(size_t)t * S_DIM + j] = qsd;
      st_coh_f1_fence(stoch_out + (size_t)t * S_DIM + j, qm + qsd * nz);
    }
    grid_bar(flags, bid, ++gen, tid);
  }
}

// C[m,n] = act( sum_k Xc[m,k] * W[n*ldw + woff + k] + bias[n] )
template <int ACT>
__global__ __launch_bounds__(256) void gemm_xwT(
    const float* __restrict__ X1, int ldx1,
    const float* __restrict__ X2, int ldx2, int ksplit,
    const float* __restrict__ W, int ldw, int woff,
    const float* __restrict__ bias,
    float* __restrict__ C, int ldc,
    int M, int N, int K)
{
  __shared__ float Xs[16][65];
  __shared__ float Ws[16][65];
  const int tid = threadIdx.x;
  const int tx = tid & 15, ty = tid >> 4;
  const int m0 = blockIdx.y * 64, n0 = blockIdx.x * 64;
  const int lrow = tid >> 2;
  const int kq4  = (tid & 3) * 4;
  float acc[4][4] = {};
  for (int k0 = 0; k0 < K; k0 += 16) {
    {
      const int m = m0 + lrow;
      #pragma unroll
      for (int j = 0; j < 4; ++j) {
        const int k = k0 + kq4 + j;
        float v = 0.f;
        if (m < M)
          v = (k < ksplit) ? X1[(size_t)m * ldx1 + k]
                           : X2[(size_t)m * ldx2 + (k - ksplit)];
        Xs[kq4 + j][lrow] = v;
      }
      const int n = n0 + lrow;
      #pragma unroll
      for (int j = 0; j < 4; ++j) {
        const int k = k0 + kq4 + j;
        Ws[kq4 + j][lrow] = (n < N) ? W[(size_t)n * ldw + woff + k] : 0.f;
      }
    }
    __syncthreads();
    #pragma unroll
    for (int kk = 0; kk < 16; ++kk) {
      float a[4], b[4];
      #pragma unroll
      for (int i = 0; i < 4; ++i) a[i] = Xs[kk][ty * 4 + i];
      #pragma unroll
      for (int j = 0; j < 4; ++j) b[j] = Ws[kk][tx * 4 + j];
      #pragma unroll
      for (int i = 0; i < 4; ++i)
        #pragma unroll
        for (int j = 0; j < 4; ++j)
          acc[i][j] += a[i] * b[j];
    }
    __syncthreads();
  }
  #pragma unroll
  for (int i = 0; i < 4; ++i) {
    const int m = m0 + ty * 4 + i;
    if (m >= M) continue;
    #pragma unroll
    for (int j = 0; j < 4; ++j) {
      const int n = n0 + tx * 4 + j;
      if (n >= N) continue;
      float v = acc[i][j] + bias[n];
      if (ACT == 1) v = eluf(v);
      if (ACT == 2) {
        if (n < 1024) C[(size_t)m * 1024 + n] = v;
        else          C[(size_t)m * 1024 + (n - 1024) + 1024 * 1024] = softplusf(v) + 0.1f;
      } else {
        C[(size_t)m * ldc + n] = v;
      }
    }
  }
}

extern "C" void kernel_launch(void* const* d_in, const int* in_sizes, int n_in,
                              void* d_out, int out_size, void* d_ws, size_t ws_size,
                              hipStream_t stream)
{
  const float* obs      = (const float*)d_in[0];
  const float* acts     = (const float*)d_in[1];
  const float* noise    = (const float*)d_in[2];
  const float* enc_w    = (const float*)d_in[3];
  const float* enc_b    = (const float*)d_in[4];
  const float* dec_w    = (const float*)d_in[5];
  const float* dec_b    = (const float*)d_in[6];
  const float* p_enc_w  = (const float*)d_in[7];
  const float* p_enc_b  = (const float*)d_in[8];
  const float* gru_wih  = (const float*)d_in[9];
  const float* gru_whh  = (const float*)d_in[10];
  const float* gru_b    = (const float*)d_in[11];
  const float* gru_bn   = (const float*)d_in[12];
  const float* p_dec1_w = (const float*)d_in[13];
  const float* p_dec1_b = (const float*)d_in[14];
  const float* p_dec2_w = (const float*)d_in[15];
  const float* p_dec2_b = (const float*)d_in[16];
  const float* q_enc_w  = (const float*)d_in[17];
  const float* q_enc_b  = (const float*)d_in[18];
  const float* q_dec_w  = (const float*)d_in[19];
  const float* q_dec_b  = (const float*)d_in[20];

  float* out   = (float*)d_out;
  float* stoch = out;                     // [1024,1024]
  float* det   = out + 1048576;           // [1024,2048]
  float* outs  = out + 3145728;           // [1024,1026]
  float* qmu   = out + 4196352;           // [1024,1024]
  float* qstd  = out + 5244928;           // [1024,1024]
  float* pmu   = out + 6293504;           // [1024,1024] (pstd adjacent)

  float* ws       = (float*)d_ws;
  float* pre_act  = ws;                          // 2,097,152 f
  float* pre_e    = ws + 2097152;                // 2,097,152 f
  float* emb      = ws + 4194304;                // 2,097,152 f
  float* xbuf     = ws + 6291456;                // 2048 f
  float* qbuf     = ws + 6293504;                // 2048 f
  unsigned* flags = (unsigned*)(ws + 6295552);   // 256 u32 packed (16B aligned)
  ushort_t* wpack = (ushort_t*)(ws + 6299648);
  ushort_t* wps_h = wpack;                       //  2,097,152 us
  ushort_t* wih_h = wps_h + 2097152;             // 12,582,912 us
  ushort_t* whh_h = wih_h + 12582912;            // 12,582,912 us
  ushort_t* wqe_h = whh_h + 12582912;            //  4,194,304 us
  ushort_t* wqd_h = wqe_h + 4194304;             //  4,194,304 us

  init_flags<<<dim3(1), dim3(256), 0, stream>>>(flags);

  // bf16 pack with chunk swizzle
  pack_swz<<<dim3(1024), dim3(256), 0, stream>>>(p_enc_w, (unsigned*)wps_h, 1088, 10, 1048576);
  pack_swz<<<dim3(1024), dim3(256), 0, stream>>>(gru_wih, (unsigned*)wih_h, 2048, 11, 6291456);
  pack_swz<<<dim3(1024), dim3(256), 0, stream>>>(gru_whh, (unsigned*)whh_h, 2048, 11, 6291456);
  pack_swz<<<dim3(1024), dim3(256), 0, stream>>>(q_enc_w, (unsigned*)wqe_h, 4096, 11, 2097152);
  pack_swz<<<dim3(1024), dim3(256), 0, stream>>>(q_dec_w, (unsigned*)wqd_h, 2048, 11, 2097152);

  dim3 blk(256);
  gemm_xwT<0><<<dim3(32, 16), blk, 0, stream>>>(
      acts, 64, acts, 64, 64, p_enc_w, 1088, 1024, p_enc_b, pre_act, 2048, 1024, 2048, 64);
  gemm_xwT<1><<<dim3(32, 16), blk, 0, stream>>>(
      obs, 1024, obs, 1024, 1024, enc_w, 1024, 0, enc_b, emb, 2048, 1024, 2048, 1024);
  gemm_xwT<0><<<dim3(32, 16), blk, 0, stream>>>(
      emb, 2048, emb, 2048, 2048, q_enc_w, 4096, 2048, q_enc_b, pre_e, 2048, 1024, 2048, 2048);

  rssm_seq<<<dim3(NWG), dim3(NTHR), 0, stream>>>(
      pre_act, pre_e, xbuf, qbuf, flags,
      wps_h, wih_h, whh_h, gru_b, gru_bn, wqe_h, wqd_h,
      q_dec_b, noise, stoch, det, qmu, qstd);

  gemm_xwT<1><<<dim3(32, 16), blk, 0, stream>>>(
      det, 2048, det, 2048, 2048, p_dec1_w, 2048, 0, p_dec1_b, emb, 2048, 1024, 2048, 2048);
  gemm_xwT<2><<<dim3(32, 16), blk, 0, stream>>>(
      emb, 2048, emb, 2048, 2048, p_dec2_w, 2048, 0, p_dec2_b, pmu, 1024, 1024, 2048, 2048);
  gemm_xwT<0><<<dim3(17, 16), blk, 0, stream>>>(
      stoch, 1024, det, 2048, 1024, dec_w, 3072, 0, dec_b, outs, 1026, 1024, 1026, 3072);
}

// Round 6
// 40257.639 us; speedup vs baseline: 1.2143x; 1.2143x over previous
//
#include <hip/hip_runtime.h>
#include <cstdint>
#include <cstddef>

#define T_STEPS 1024
#define S_DIM   1024
#define A_DIM   64
#define D_DIM   2048
#define H_DIM   2048
#define NWG     256
#define NTHR    1024   // 16 waves per WG, 1 WG per CU

typedef unsigned short ushort_t;

__device__ __forceinline__ float eluf(float v)      { return v > 0.f ? v : expm1f(v); }
__device__ __forceinline__ float softplusf(float v) { return v > 20.f ? v : log1pf(expf(v)); }
__device__ __forceinline__ float sigmoidf_(float v) { return 1.f / (1.f + expf(-v)); }

__device__ __forceinline__ float wave_reduce(float v) {
  #pragma unroll
  for (int off = 32; off > 0; off >>= 1) v += __shfl_xor(v, off, 64);
  return v;
}

// unpack a u32 holding two bf16 (e0 = low half, e1 = high half)
__device__ __forceinline__ float2 bf2(unsigned u) {
  float2 r;
  r.x = __uint_as_float(u << 16);
  r.y = __uint_as_float(u & 0xffff0000u);
  return r;
}
__device__ __forceinline__ ushort_t f2bf_rne(float f) {
  unsigned u = __float_as_uint(f);
  u += 0x7fffu + ((u >> 16) & 1u);
  return (ushort_t)(u >> 16);
}

// ---- coherent (cross-XCD) accesses: bypass L1/L2, hit the coherence point.
__device__ __forceinline__ float4 ld_coh_f4(const float* p) {
  float4 v;
  asm volatile("global_load_dwordx4 %0, %1, off sc0 sc1\n\ts_waitcnt vmcnt(0)"
               : "=v"(v) : "v"(p) : "memory");
  return v;
}
// store + completion fence (so grid_bar needn't drain vmcnt)
__device__ __forceinline__ void st_coh_f1_fence(float* p, float v) {
  asm volatile("global_store_dword %0, %1, off sc0 sc1\n\ts_waitcnt vmcnt(0)"
               :: "v"(p), "v"(v) : "memory");
}

// pinned (volatile) weight load: cannot be rematerialized/sunk into the loop,
// so the destination VGPRs stay live across the whole scan.
#define LD_PIN_U4(dst, addr) \
  asm volatile("global_load_dwordx4 %0, %1, off" : "=v"(dst) : "v"(addr))

__global__ void init_flags(unsigned* f) { f[threadIdx.x] = 0u; }

// Packed-flag grid barrier: 256 contiguous u32; lane l polls flags[4l..4l+3]
// with ONE dwordx4 round trip.
__device__ __forceinline__ void grid_bar(unsigned* flags, int bid, unsigned gen, int tid) {
  __syncthreads();   // all epilogue stores already vmcnt-fenced per-thread
  if (tid == 0)
    asm volatile("global_store_dword %0, %1, off sc0 sc1"
                 :: "v"(flags + bid), "v"(gen) : "memory");
  if (tid < 64) {
    const unsigned* p = flags + tid * 4;
    bool done;
    do {
      uint4 f;
      asm volatile("global_load_dwordx4 %0, %1, off sc0 sc1\n\ts_waitcnt vmcnt(0)"
                   : "=v"(f) : "v"(p) : "memory");
      done = (f.x >= gen) && (f.y >= gen) && (f.z >= gen) && (f.w >= gen);
    } while (!__all(done));
  }
  __syncthreads();
}

// fp32 -> bf16 pack with per-512-chunk column swizzle:
// dst pos (within row): chunk*512 + l*8 + p*2 + e  <-  src k: chunk*512 + p*128 + l*2 + e
__global__ __launch_bounds__(256) void pack_swz(
    const float* __restrict__ src, unsigned* __restrict__ dst,
    int src_ld, int lc /*log2 cols*/, size_t total2 /*u32 count*/)
{
  for (size_t u = (size_t)blockIdx.x * 256 + threadIdx.x; u < total2;
       u += (size_t)gridDim.x * 256) {
    const size_t pos = u * 2;
    const size_t row = pos >> lc;
    const int pcol  = (int)(pos & (((size_t)1 << lc) - 1));
    const int chunk = pcol >> 9;
    const int off   = pcol & 511;
    const int l     = off >> 3;
    const int p     = (off >> 1) & 3;
    const float2 v  = *(const float2*)(src + row * src_ld + chunk * 512 + p * 128 + l * 2);
    dst[u] = (unsigned)f2bf_rne(v.x) | ((unsigned)f2bf_rne(v.y) << 16);
  }
}

// dot of one swizzled 512-chunk (uint4 = 8 bf16) against LDS chunk
__device__ __forceinline__ float chunk_dot(const uint4 w, const float* vchunk, int lane) {
  float acc = 0.f; float2 p, a;
  a = *(const float2*)(vchunk + lane * 2 +   0); p = bf2(w.x); acc += p.x*a.x + p.y*a.y;
  a = *(const float2*)(vchunk + lane * 2 + 128); p = bf2(w.y); acc += p.x*a.x + p.y*a.y;
  a = *(const float2*)(vchunk + lane * 2 + 256); p = bf2(w.z); acc += p.x*a.x + p.y*a.y;
  a = *(const float2*)(vchunk + lane * 2 + 384); p = bf2(w.w); acc += p.x*a.x + p.y*a.y;
  return acc;
}

__global__ __launch_bounds__(NTHR, 4) void rssm_seq(
    const float* __restrict__ pre_act, const float* __restrict__ pre_e,
    float* __restrict__ xbuf, float* __restrict__ qbuf, unsigned* __restrict__ flags,
    const ushort_t* __restrict__ wps,
    const ushort_t* __restrict__ wih, const ushort_t* __restrict__ whh,
    const float* __restrict__ gru_b, const float* __restrict__ gru_bn,
    const ushort_t* __restrict__ wqe, const ushort_t* __restrict__ wqd,
    const float* __restrict__ q_dec_b, const float* __restrict__ noise,
    float* __restrict__ stoch_out, float* __restrict__ det_out,
    float* __restrict__ qmu_out, float* __restrict__ qstd_out)
{
  __shared__ float sp[1024];      // stoch_prev
  __shared__ float xs[2048];      // x vector
  __shared__ float ds[2048];      // det_prev; becomes det_t in stage3, persists to next step
  __shared__ float qs[2048];      // q vector
  __shared__ float part1[8][2];
  __shared__ float partg[8][6];
  __shared__ float part3[8][2];
  __shared__ float part4[8][2];

  const int tid  = threadIdx.x;
  const int wv   = tid >> 6;          // 0..15
  const int lane = tid & 63;
  const int bid  = blockIdx.x;
  const int r0   = bid * 8;           // 8 rows of 2048 per WG
  unsigned gen = 0;

  // ------------- resident weights: volatile-asm loads, pinned in VGPRs for the scan -------------
  uint4 w1;       // stage1: row r0+(wv&7), k-chunk (wv>>3) of 1024
  uint4 w2[12];   // stage2: 3 gate rows (ih for wv<8, hh for wv>=8) of row r0+(wv&7), K=2048
  uint4 w3[2];    // stage3: row r0+(wv&7), k-half (wv>>3) of 2048
  uint4 w4[2];    // stage4: dot (wv>>1), k-half (wv&1)
  {
    const int row = wv & 7, half = wv >> 3;
    LD_PIN_U4(w1, (const uint4*)(wps + (size_t)(r0 + row) * 1024) + half * 64 + lane);

    const ushort_t* wbase = (wv < 8) ? wih : whh;
    const size_t i = (size_t)(r0 + row);
    #pragma unroll
    for (int g = 0; g < 3; ++g) {
      const uint4* wr = (const uint4*)(wbase + (i + (size_t)g * 2048) * 2048);
      #pragma unroll
      for (int j = 0; j < 4; ++j) LD_PIN_U4(w2[g * 4 + j], wr + j * 64 + lane);
    }
    {
      const uint4* wr = (const uint4*)(wqe + (size_t)(r0 + row) * 2048);
      LD_PIN_U4(w3[0], wr + (2 * half)     * 64 + lane);
      LD_PIN_U4(w3[1], wr + (2 * half + 1) * 64 + lane);
    }
    {
      const int dot = wv >> 1, h4 = wv & 1;
      const int jg = bid * 4 + (dot & 3), sel = dot >> 2;
      const uint4* wr = (const uint4*)(wqd + (size_t)(jg + sel * 1024) * 2048);
      LD_PIN_U4(w4[0], wr + (2 * h4)     * 64 + lane);
      LD_PIN_U4(w4[1], wr + (2 * h4 + 1) * 64 + lane);
    }
    asm volatile("s_waitcnt vmcnt(0)" ::: "memory");
  }

  // per-row constants, resident
  float gb_r = 0.f, gb_z = 0.f, gb_n = 0.f, gbn = 0.f, qdb_m = 0.f, qdb_s = 0.f;
  if (tid < 8) {
    gb_r = gru_b[r0 + tid];
    gb_z = gru_b[r0 + tid + 2048];
    gb_n = gru_b[r0 + tid + 4096];
    gbn  = gru_bn[r0 + tid];
  }
  if (tid < 4) {
    qdb_m = q_dec_b[bid * 4 + tid];
    qdb_s = q_dec_b[bid * 4 + tid + 1024];
  }

  // det_prev = 0 for t=0 (ds persists across iterations thereafter)
  if (tid < 512) ((float4*)ds)[tid] = float4{0.f, 0.f, 0.f, 0.f};

  for (int t = 0; t < T_STEPS; ++t) {
    // issue this step's small uniform loads early (consumed in epilogues)
    float pa = 0.f, pe = 0.f, nz = 0.f;
    if (tid < 8) {
      pa = pre_act[(size_t)t * D_DIM + r0 + tid];
      pe = pre_e  [(size_t)t * H_DIM + r0 + tid];
    }
    if (tid < 4) nz = noise[(size_t)t * S_DIM + bid * 4 + tid];

    // stage stoch_prev
    if (tid < 256) {
      ((float4*)sp)[tid] = (t > 0)
        ? ld_coh_f4(stoch_out + (size_t)(t - 1) * S_DIM + tid * 4)
        : float4{0.f, 0.f, 0.f, 0.f};
    }
    __syncthreads();

    // ================= stage 1: x = elu(Wps @ stoch_prev + pre_act[t]) =================
    {
      const int row = wv & 7, half = wv >> 3;
      float acc = wave_reduce(chunk_dot(w1, sp + half * 512, lane));
      if (lane == 0) part1[row][half] = acc;
    }
    __syncthreads();
    if (tid < 8)
      st_coh_f1_fence(xbuf + r0 + tid, eluf(part1[tid][0] + part1[tid][1] + pa));
    grid_bar(flags, bid, ++gen, tid);

    // ================= stage 2: GRU -> det[t] =================
    if (tid < 512) ((float4*)xs)[tid] = ld_coh_f4(xbuf + tid * 4);
    __syncthreads();
    {
      const float* vec = (wv < 8) ? xs : ds;
      float a0 = 0.f, a1 = 0.f, a2 = 0.f;
      #pragma unroll
      for (int j = 0; j < 4; ++j) {
        const float* b = vec + j * 512 + lane * 2;
        const float2 v0 = *(const float2*)(b);
        const float2 v1 = *(const float2*)(b + 128);
        const float2 v2 = *(const float2*)(b + 256);
        const float2 v3 = *(const float2*)(b + 384);
        float2 p; uint4 w;
        w = w2[j];
        p = bf2(w.x); a0 += p.x*v0.x + p.y*v0.y;
        p = bf2(w.y); a0 += p.x*v1.x + p.y*v1.y;
        p = bf2(w.z); a0 += p.x*v2.x + p.y*v2.y;
        p = bf2(w.w); a0 += p.x*v3.x + p.y*v3.y;
        w = w2[4 + j];
        p = bf2(w.x); a1 += p.x*v0.x + p.y*v0.y;
        p = bf2(w.y); a1 += p.x*v1.x + p.y*v1.y;
        p = bf2(w.z); a1 += p.x*v2.x + p.y*v2.y;
        p = bf2(w.w); a1 += p.x*v3.x + p.y*v3.y;
        w = w2[8 + j];
        p = bf2(w.x); a2 += p.x*v0.x + p.y*v0.y;
        p = bf2(w.y); a2 += p.x*v1.x + p.y*v1.y;
        p = bf2(w.z); a2 += p.x*v2.x + p.y*v2.y;
        p = bf2(w.w); a2 += p.x*v3.x + p.y*v3.y;
      }
      a0 = wave_reduce(a0); a1 = wave_reduce(a1); a2 = wave_reduce(a2);
      if (lane == 0) {
        const int row = wv & 7;
        if (wv < 8) { partg[row][0] = a0; partg[row][1] = a1; partg[row][2] = a2; }
        else        { partg[row][3] = a0; partg[row][4] = a1; partg[row][5] = a2; }
      }
    }
    __syncthreads();
    if (tid < 8) {
      const float r_ = sigmoidf_(partg[tid][0] + gb_r + partg[tid][3]);
      const float z_ = sigmoidf_(partg[tid][1] + gb_z + partg[tid][4]);
      const float n_ = tanhf(partg[tid][2] + gb_n + r_ * (partg[tid][5] + gbn));
      st_coh_f1_fence(det_out + (size_t)t * D_DIM + r0 + tid, n_ + z_ * (ds[r0 + tid] - n_));
    }
    grid_bar(flags, bid, ++gen, tid);

    // ================= stage 3: q = elu(Wqe @ det_t + pre_e[t]) =================
    if (tid < 512) ((float4*)ds)[tid] = ld_coh_f4(det_out + (size_t)t * D_DIM + tid * 4);
    __syncthreads();
    {
      const int row = wv & 7, half = wv >> 3;
      float acc = chunk_dot(w3[0], ds + (2 * half) * 512, lane)
                + chunk_dot(w3[1], ds + (2 * half + 1) * 512, lane);
      acc = wave_reduce(acc);
      if (lane == 0) part3[row][half] = acc;
    }
    __syncthreads();
    if (tid < 8)
      st_coh_f1_fence(qbuf + r0 + tid, eluf(part3[tid][0] + part3[tid][1] + pe));
    grid_bar(flags, bid, ++gen, tid);

    // ================= stage 4: posterior head + sample =================
    if (tid < 512) ((float4*)qs)[tid] = ld_coh_f4(qbuf + tid * 4);
    __syncthreads();
    {
      const int dot = wv >> 1, half = wv & 1;
      float acc = chunk_dot(w4[0], qs + (2 * half) * 512, lane)
                + chunk_dot(w4[1], qs + (2 * half + 1) * 512, lane);
      acc = wave_reduce(acc);
      if (lane == 0) part4[dot][half] = acc;
    }
    __syncthreads();
    if (tid < 4) {
      const int j = bid * 4 + tid;
      const float qm  = part4[tid][0] + part4[tid][1] + qdb_m;
      const float qsd = softplusf(part4[tid + 4][0] + part4[tid + 4][1] + qdb_s) + 0.1f;
      qmu_out [(size_t)t * S_DIM + j] = qm;
      qstd_out[(size_t)t * S_DIM + j] = qsd;
      st_coh_f1_fence(stoch_out + (size_t)t * S_DIM + j, qm + qsd * nz);
    }
    grid_bar(flags, bid, ++gen, tid);
  }
}

// C[m,n] = act( sum_k Xc[m,k] * W[n*ldw + woff + k] + bias[n] )
template <int ACT>
__global__ __launch_bounds__(256) void gemm_xwT(
    const float* __restrict__ X1, int ldx1,
    const float* __restrict__ X2, int ldx2, int ksplit,
    const float* __restrict__ W, int ldw, int woff,
    const float* __restrict__ bias,
    float* __restrict__ C, int ldc,
    int M, int N, int K)
{
  __shared__ float Xs[16][65];
  __shared__ float Ws[16][65];
  const int tid = threadIdx.x;
  const int tx = tid & 15, ty = tid >> 4;
  const int m0 = blockIdx.y * 64, n0 = blockIdx.x * 64;
  const int lrow = tid >> 2;
  const int kq4  = (tid & 3) * 4;
  float acc[4][4] = {};
  for (int k0 = 0; k0 < K; k0 += 16) {
    {
      const int m = m0 + lrow;
      #pragma unroll
      for (int j = 0; j < 4; ++j) {
        const int k = k0 + kq4 + j;
        float v = 0.f;
        if (m < M)
          v = (k < ksplit) ? X1[(size_t)m * ldx1 + k]
                           : X2[(size_t)m * ldx2 + (k - ksplit)];
        Xs[kq4 + j][lrow] = v;
      }
      const int n = n0 + lrow;
      #pragma unroll
      for (int j = 0; j < 4; ++j) {
        const int k = k0 + kq4 + j;
        Ws[kq4 + j][lrow] = (n < N) ? W[(size_t)n * ldw + woff + k] : 0.f;
      }
    }
    __syncthreads();
    #pragma unroll
    for (int kk = 0; kk < 16; ++kk) {
      float a[4], b[4];
      #pragma unroll
      for (int i = 0; i < 4; ++i) a[i] = Xs[kk][ty * 4 + i];
      #pragma unroll
      for (int j = 0; j < 4; ++j) b[j] = Ws[kk][tx * 4 + j];
      #pragma unroll
      for (int i = 0; i < 4; ++i)
        #pragma unroll
        for (int j = 0; j < 4; ++j)
          acc[i][j] += a[i] * b[j];
    }
    __syncthreads();
  }
  #pragma unroll
  for (int i = 0; i < 4; ++i) {
    const int m = m0 + ty * 4 + i;
    if (m >= M) continue;
    #pragma unroll
    for (int j = 0; j < 4; ++j) {
      const int n = n0 + tx * 4 + j;
      if (n >= N) continue;
      float v = acc[i][j] + bias[n];
      if (ACT == 1) v = eluf(v);
      if (ACT == 2) {
        if (n < 1024) C[(size_t)m * 1024 + n] = v;
        else          C[(size_t)m * 1024 + (n - 1024) + 1024 * 1024] = softplusf(v) + 0.1f;
      } else {
        C[(size_t)m * ldc + n] = v;
      }
    }
  }
}

extern "C" void kernel_launch(void* const* d_in, const int* in_sizes, int n_in,
                              void* d_out, int out_size, void* d_ws, size_t ws_size,
                              hipStream_t stream)
{
  const float* obs      = (const float*)d_in[0];
  const float* acts     = (const float*)d_in[1];
  const float* noise    = (const float*)d_in[2];
  const float* enc_w    = (const float*)d_in[3];
  const float* enc_b    = (const float*)d_in[4];
  const float* dec_w    = (const float*)d_in[5];
  const float* dec_b    = (const float*)d_in[6];
  const float* p_enc_w  = (const float*)d_in[7];
  const float* p_enc_b  = (const float*)d_in[8];
  const float* gru_wih  = (const float*)d_in[9];
  const float* gru_whh  = (const float*)d_in[10];
  const float* gru_b    = (const float*)d_in[11];
  const float* gru_bn   = (const float*)d_in[12];
  const float* p_dec1_w = (const float*)d_in[13];
  const float* p_dec1_b = (const float*)d_in[14];
  const float* p_dec2_w = (const float*)d_in[15];
  const float* p_dec2_b = (const float*)d_in[16];
  const float* q_enc_w  = (const float*)d_in[17];
  const float* q_enc_b  = (const float*)d_in[18];
  const float* q_dec_w  = (const float*)d_in[19];
  const float* q_dec_b  = (const float*)d_in[20];

  float* out   = (float*)d_out;
  float* stoch = out;                     // [1024,1024]
  float* det   = out + 1048576;           // [1024,2048]
  float* outs  = out + 3145728;           // [1024,1026]
  float* qmu   = out + 4196352;           // [1024,1024]
  float* qstd  = out + 5244928;           // [1024,1024]
  float* pmu   = out + 6293504;           // [1024,1024] (pstd adjacent)

  float* ws       = (float*)d_ws;
  float* pre_act  = ws;                          // 2,097,152 f
  float* pre_e    = ws + 2097152;                // 2,097,152 f
  float* emb      = ws + 4194304;                // 2,097,152 f
  float* xbuf     = ws + 6291456;                // 2048 f
  float* qbuf     = ws + 6293504;                // 2048 f
  unsigned* flags = (unsigned*)(ws + 6295552);   // 256 u32 packed (16B aligned)
  ushort_t* wpack = (ushort_t*)(ws + 6299648);
  ushort_t* wps_h = wpack;                       //  2,097,152 us
  ushort_t* wih_h = wps_h + 2097152;             // 12,582,912 us
  ushort_t* whh_h = wih_h + 12582912;            // 12,582,912 us
  ushort_t* wqe_h = whh_h + 12582912;            //  4,194,304 us
  ushort_t* wqd_h = wqe_h + 4194304;             //  4,194,304 us

  init_flags<<<dim3(1), dim3(256), 0, stream>>>(flags);

  // bf16 pack with chunk swizzle
  pack_swz<<<dim3(1024), dim3(256), 0, stream>>>(p_enc_w, (unsigned*)wps_h, 1088, 10, 1048576);
  pack_swz<<<dim3(1024), dim3(256), 0, stream>>>(gru_wih, (unsigned*)wih_h, 2048, 11, 6291456);
  pack_swz<<<dim3(1024), dim3(256), 0, stream>>>(gru_whh, (unsigned*)whh_h, 2048, 11, 6291456);
  pack_swz<<<dim3(1024), dim3(256), 0, stream>>>(q_enc_w, (unsigned*)wqe_h, 4096, 11, 2097152);
  pack_swz<<<dim3(1024), dim3(256), 0, stream>>>(q_dec_w, (unsigned*)wqd_h, 2048, 11, 2097152);

  dim3 blk(256);
  gemm_xwT<0><<<dim3(32, 16), blk, 0, stream>>>(
      acts, 64, acts, 64, 64, p_enc_w, 1088, 1024, p_enc_b, pre_act, 2048, 1024, 2048, 64);
  gemm_xwT<1><<<dim3(32, 16), blk, 0, stream>>>(
      obs, 1024, obs, 1024, 1024, enc_w, 1024, 0, enc_b, emb, 2048, 1024, 2048, 1024);
  gemm_xwT<0><<<dim3(32, 16), blk, 0, stream>>>(
      emb, 2048, emb, 2048, 2048, q_enc_w, 4096, 2048, q_enc_b, pre_e, 2048, 1024, 2048, 2048);

  rssm_seq<<<dim3(NWG), dim3(NTHR), 0, stream>>>(
      pre_act, pre_e, xbuf, qbuf, flags,
      wps_h, wih_h, whh_h, gru_b, gru_bn, wqe_h, wqd_h,
      q_dec_b, noise, stoch, det, qmu, qstd);

  gemm_xwT<1><<<dim3(32, 16), blk, 0, stream>>>(
      det, 2048, det, 2048, 2048, p_dec1_w, 2048, 0, p_dec1_b, emb, 2048, 1024, 2048, 2048);
  gemm_xwT<2><<<dim3(32, 16), blk, 0, stream>>>(
      emb, 2048, emb, 2048, 2048, p_dec2_w, 2048, 0, p_dec2_b, pmu, 1024, 1024, 2048, 2048);
  gemm_xwT<0><<<dim3(17, 16), blk, 0, stream>>>(
      stoch, 1024, det, 2048, 1024, dec_w, 3072, 0, dec_b, outs, 1026, 1024, 1026, 3072);
}

// Round 7
// 40181.842 us; speedup vs baseline: 1.2166x; 1.0019x over previous
//
#include <hip/hip_runtime.h>
#include <cstdint>
#include <cstddef>

#define T_STEPS 1024
#define S_DIM   1024
#define A_DIM   64
#define D_DIM   2048
#define H_DIM   2048
#define NWG     256
#define NTHR    1024   // 16 waves per WG, 1 WG per CU

typedef unsigned short ushort_t;

__device__ __forceinline__ float eluf(float v)      { return v > 0.f ? v : expm1f(v); }
__device__ __forceinline__ float softplusf(float v) { return v > 20.f ? v : log1pf(expf(v)); }
__device__ __forceinline__ float sigmoidf_(float v) { return 1.f / (1.f + expf(-v)); }

__device__ __forceinline__ float wave_reduce(float v) {
  #pragma unroll
  for (int off = 32; off > 0; off >>= 1) v += __shfl_xor(v, off, 64);
  return v;
}

// unpack a u32 holding two bf16 (e0 = low half, e1 = high half)
__device__ __forceinline__ float2 bf2(unsigned u) {
  float2 r;
  r.x = __uint_as_float(u << 16);
  r.y = __uint_as_float(u & 0xffff0000u);
  return r;
}
__device__ __forceinline__ ushort_t f2bf_rne(float f) {
  unsigned u = __float_as_uint(f);
  u += 0x7fffu + ((u >> 16) & 1u);
  return (ushort_t)(u >> 16);
}

// ---- coherent (cross-XCD) accesses: bypass L1/L2, hit the coherence point.
__device__ __forceinline__ float4 ld_coh_f4(const float* p) {
  float4 v;
  asm volatile("global_load_dwordx4 %0, %1, off sc0 sc1\n\ts_waitcnt vmcnt(0)"
               : "=v"(v) : "v"(p) : "memory");
  return v;
}
// store + completion fence (so grid_bar needn't drain vmcnt)
__device__ __forceinline__ void st_coh_f1_fence(float* p, float v) {
  asm volatile("global_store_dword %0, %1, off sc0 sc1\n\ts_waitcnt vmcnt(0)"
               :: "v"(p), "v"(v) : "memory");
}

// pinned (volatile) weight load: cannot be rematerialized/sunk into the loop.
#define LD_PIN_U4(dst, addr) \
  asm volatile("global_load_dwordx4 %0, %1, off" : "=v"(dst) : "v"(addr))

__global__ void init_flags(unsigned* f) { f[threadIdx.x] = 0u; }

// Packed-flag grid barrier: 256 contiguous u32; lane l polls flags[4l..4l+3]
// with ONE dwordx4 round trip.
__device__ __forceinline__ void grid_bar(unsigned* flags, int bid, unsigned gen, int tid) {
  __syncthreads();   // all epilogue stores already vmcnt-fenced per-thread
  if (tid == 0)
    asm volatile("global_store_dword %0, %1, off sc0 sc1"
                 :: "v"(flags + bid), "v"(gen) : "memory");
  if (tid < 64) {
    const unsigned* p = flags + tid * 4;
    bool done;
    do {
      uint4 f;
      asm volatile("global_load_dwordx4 %0, %1, off sc0 sc1\n\ts_waitcnt vmcnt(0)"
                   : "=v"(f) : "v"(p) : "memory");
      done = (f.x >= gen) && (f.y >= gen) && (f.z >= gen) && (f.w >= gen);
    } while (!__all(done));
  }
  __syncthreads();
}

// fp32 -> bf16 pack with per-512-chunk column swizzle:
// dst pos (within row): chunk*512 + l*8 + p*2 + e  <-  src k: chunk*512 + p*128 + l*2 + e
__global__ __launch_bounds__(256) void pack_swz(
    const float* __restrict__ src, unsigned* __restrict__ dst,
    int src_ld, int lc /*log2 cols*/, size_t total2 /*u32 count*/)
{
  for (size_t u = (size_t)blockIdx.x * 256 + threadIdx.x; u < total2;
       u += (size_t)gridDim.x * 256) {
    const size_t pos = u * 2;
    const size_t row = pos >> lc;
    const int pcol  = (int)(pos & (((size_t)1 << lc) - 1));
    const int chunk = pcol >> 9;
    const int off   = pcol & 511;
    const int l     = off >> 3;
    const int p     = (off >> 1) & 3;
    const float2 v  = *(const float2*)(src + row * src_ld + chunk * 512 + p * 128 + l * 2);
    dst[u] = (unsigned)f2bf_rne(v.x) | ((unsigned)f2bf_rne(v.y) << 16);
  }
}

// dot of one swizzled 512-chunk (uint4 = 8 bf16) against LDS chunk
__device__ __forceinline__ float chunk_dot(const uint4 w, const float* vchunk, int lane) {
  float acc = 0.f; float2 p, a;
  a = *(const float2*)(vchunk + lane * 2 +   0); p = bf2(w.x); acc += p.x*a.x + p.y*a.y;
  a = *(const float2*)(vchunk + lane * 2 + 128); p = bf2(w.y); acc += p.x*a.x + p.y*a.y;
  a = *(const float2*)(vchunk + lane * 2 + 256); p = bf2(w.z); acc += p.x*a.x + p.y*a.y;
  a = *(const float2*)(vchunk + lane * 2 + 384); p = bf2(w.w); acc += p.x*a.x + p.y*a.y;
  return acc;
}

__global__ __launch_bounds__(NTHR)
__attribute__((amdgpu_waves_per_eu(4, 4)))   // pin occupancy target: 4 waves/SIMD -> 128-VGPR budget, no spill
void rssm_seq(
    const float* __restrict__ pre_act, const float* __restrict__ pre_e,
    float* __restrict__ xbuf, float* __restrict__ qbuf, unsigned* __restrict__ flags,
    const ushort_t* __restrict__ wps,
    const ushort_t* __restrict__ wih, const ushort_t* __restrict__ whh,
    const float* __restrict__ gru_b, const float* __restrict__ gru_bn,
    const ushort_t* __restrict__ wqe, const ushort_t* __restrict__ wqd,
    const float* __restrict__ q_dec_b, const float* __restrict__ noise,
    float* __restrict__ stoch_out, float* __restrict__ det_out,
    float* __restrict__ qmu_out, float* __restrict__ qstd_out)
{
  __shared__ float sp[1024];      // stoch_prev
  __shared__ float xs[2048];      // x vector
  __shared__ float ds[2048];      // det_prev; becomes det_t in stage3, persists to next step
  __shared__ float qs[2048];      // q vector
  __shared__ float part1[8][2];
  __shared__ float partg[8][6];
  __shared__ float part3[8][2];
  __shared__ float part4[8][2];

  const int tid  = threadIdx.x;
  const int wv   = tid >> 6;          // 0..15
  const int lane = tid & 63;
  const int bid  = blockIdx.x;
  const int r0   = bid * 8;           // 8 rows of 2048 per WG
  unsigned gen = 0;

  // ------------- resident weights: volatile-asm loads, pinned in VGPRs for the scan -------------
  uint4 w1;       // stage1: row r0+(wv&7), k-chunk (wv>>3) of 1024
  uint4 w2[12];   // stage2: 3 gate rows (ih for wv<8, hh for wv>=8) of row r0+(wv&7), K=2048
  uint4 w3[2];    // stage3: row r0+(wv&7), k-half (wv>>3) of 2048
  uint4 w4[2];    // stage4: dot (wv>>1), k-half (wv&1)
  {
    const int row = wv & 7, half = wv >> 3;
    LD_PIN_U4(w1, (const uint4*)(wps + (size_t)(r0 + row) * 1024) + half * 64 + lane);

    const ushort_t* wbase = (wv < 8) ? wih : whh;
    const size_t i = (size_t)(r0 + row);
    #pragma unroll
    for (int g = 0; g < 3; ++g) {
      const uint4* wr = (const uint4*)(wbase + (i + (size_t)g * 2048) * 2048);
      #pragma unroll
      for (int j = 0; j < 4; ++j) LD_PIN_U4(w2[g * 4 + j], wr + j * 64 + lane);
    }
    {
      const uint4* wr = (const uint4*)(wqe + (size_t)(r0 + row) * 2048);
      LD_PIN_U4(w3[0], wr + (2 * half)     * 64 + lane);
      LD_PIN_U4(w3[1], wr + (2 * half + 1) * 64 + lane);
    }
    {
      const int dot = wv >> 1, h4 = wv & 1;
      const int jg = bid * 4 + (dot & 3), sel = dot >> 2;
      const uint4* wr = (const uint4*)(wqd + (size_t)(jg + sel * 1024) * 2048);
      LD_PIN_U4(w4[0], wr + (2 * h4)     * 64 + lane);
      LD_PIN_U4(w4[1], wr + (2 * h4 + 1) * 64 + lane);
    }
    asm volatile("s_waitcnt vmcnt(0)" ::: "memory");
  }

  // per-row constants, resident
  float gb_r = 0.f, gb_z = 0.f, gb_n = 0.f, gbn = 0.f, qdb_m = 0.f, qdb_s = 0.f;
  if (tid < 8) {
    gb_r = gru_b[r0 + tid];
    gb_z = gru_b[r0 + tid + 2048];
    gb_n = gru_b[r0 + tid + 4096];
    gbn  = gru_bn[r0 + tid];
  }
  if (tid < 4) {
    qdb_m = q_dec_b[bid * 4 + tid];
    qdb_s = q_dec_b[bid * 4 + tid + 1024];
  }

  // det_prev = 0 for t=0 (ds persists across iterations thereafter)
  if (tid < 512) ((float4*)ds)[tid] = float4{0.f, 0.f, 0.f, 0.f};

  for (int t = 0; t < T_STEPS; ++t) {
    // issue this step's small uniform loads early (consumed in epilogues)
    float pa = 0.f, pe = 0.f, nz = 0.f;
    if (tid < 8) {
      pa = pre_act[(size_t)t * D_DIM + r0 + tid];
      pe = pre_e  [(size_t)t * H_DIM + r0 + tid];
    }
    if (tid < 4) nz = noise[(size_t)t * S_DIM + bid * 4 + tid];

    // stage stoch_prev
    if (tid < 256) {
      ((float4*)sp)[tid] = (t > 0)
        ? ld_coh_f4(stoch_out + (size_t)(t - 1) * S_DIM + tid * 4)
        : float4{0.f, 0.f, 0.f, 0.f};
    }
    __syncthreads();

    // ================= stage 1: x = elu(Wps @ stoch_prev + pre_act[t]) =================
    {
      const int row = wv & 7, half = wv >> 3;
      float acc = wave_reduce(chunk_dot(w1, sp + half * 512, lane));
      if (lane == 0) part1[row][half] = acc;
    }
    __syncthreads();
    if (tid < 8)
      st_coh_f1_fence(xbuf + r0 + tid, eluf(part1[tid][0] + part1[tid][1] + pa));
    grid_bar(flags, bid, ++gen, tid);

    // ================= stage 2: GRU -> det[t] =================
    if (tid < 512) ((float4*)xs)[tid] = ld_coh_f4(xbuf + tid * 4);
    __syncthreads();
    {
      const float* vec = (wv < 8) ? xs : ds;
      float a0 = 0.f, a1 = 0.f, a2 = 0.f;
      #pragma unroll
      for (int j = 0; j < 4; ++j) {
        const float* b = vec + j * 512 + lane * 2;
        const float2 v0 = *(const float2*)(b);
        const float2 v1 = *(const float2*)(b + 128);
        const float2 v2 = *(const float2*)(b + 256);
        const float2 v3 = *(const float2*)(b + 384);
        float2 p; uint4 w;
        w = w2[j];
        p = bf2(w.x); a0 += p.x*v0.x + p.y*v0.y;
        p = bf2(w.y); a0 += p.x*v1.x + p.y*v1.y;
        p = bf2(w.z); a0 += p.x*v2.x + p.y*v2.y;
        p = bf2(w.w); a0 += p.x*v3.x + p.y*v3.y;
        w = w2[4 + j];
        p = bf2(w.x); a1 += p.x*v0.x + p.y*v0.y;
        p = bf2(w.y); a1 += p.x*v1.x + p.y*v1.y;
        p = bf2(w.z); a1 += p.x*v2.x + p.y*v2.y;
        p = bf2(w.w); a1 += p.x*v3.x + p.y*v3.y;
        w = w2[8 + j];
        p = bf2(w.x); a2 += p.x*v0.x + p.y*v0.y;
        p = bf2(w.y); a2 += p.x*v1.x + p.y*v1.y;
        p = bf2(w.z); a2 += p.x*v2.x + p.y*v2.y;
        p = bf2(w.w); a2 += p.x*v3.x + p.y*v3.y;
      }
      a0 = wave_reduce(a0); a1 = wave_reduce(a1); a2 = wave_reduce(a2);
      if (lane == 0) {
        const int row = wv & 7;
        if (wv < 8) { partg[row][0] = a0; partg[row][1] = a1; partg[row][2] = a2; }
        else        { partg[row][3] = a0; partg[row][4] = a1; partg[row][5] = a2; }
      }
    }
    __syncthreads();
    if (tid < 8) {
      const float r_ = sigmoidf_(partg[tid][0] + gb_r + partg[tid][3]);
      const float z_ = sigmoidf_(partg[tid][1] + gb_z + partg[tid][4]);
      const float n_ = tanhf(partg[tid][2] + gb_n + r_ * (partg[tid][5] + gbn));
      st_coh_f1_fence(det_out + (size_t)t * D_DIM + r0 + tid, n_ + z_ * (ds[r0 + tid] - n_));
    }
    grid_bar(flags, bid, ++gen, tid);

    // ================= stage 3: q = elu(Wqe @ det_t + pre_e[t]) =================
    if (tid < 512) ((float4*)ds)[tid] = ld_coh_f4(det_out + (size_t)t * D_DIM + tid * 4);
    __syncthreads();
    {
      const int row = wv & 7, half = wv >> 3;
      float acc = chunk_dot(w3[0], ds + (2 * half) * 512, lane)
                + chunk_dot(w3[1], ds + (2 * half + 1) * 512, lane);
      acc = wave_reduce(acc);
      if (lane == 0) part3[row][half] = acc;
    }
    __syncthreads();
    if (tid < 8)
      st_coh_f1_fence(qbuf + r0 + tid, eluf(part3[tid][0] + part3[tid][1] + pe));
    grid_bar(flags, bid, ++gen, tid);

    // ================= stage 4: posterior head + sample =================
    if (tid < 512) ((float4*)qs)[tid] = ld_coh_f4(qbuf + tid * 4);
    __syncthreads();
    {
      const int dot = wv >> 1, half = wv & 1;
      float acc = chunk_dot(w4[0], qs + (2 * half) * 512, lane)
                + chunk_dot(w4[1], qs + (2 * half + 1) * 512, lane);
      acc = wave_reduce(acc);
      if (lane == 0) part4[dot][half] = acc;
    }
    __syncthreads();
    if (tid < 4) {
      const int j = bid * 4 + tid;
      const float qm  = part4[tid][0] + part4[tid][1] + qdb_m;
      const float qsd = softplusf(part4[tid + 4][0] + part4[tid + 4][1] + qdb_s) + 0.1f;
      qmu_out [(size_t)t * S_DIM + j] = qm;
      qstd_out[(size_t)t * S_DIM + j] = qsd;
      st_coh_f1_fence(stoch_out + (size_t)t * S_DIM + j, qm + qsd * nz);
    }
    grid_bar(flags, bid, ++gen, tid);
  }
}

// C[m,n] = act( sum_k Xc[m,k] * W[n*ldw + woff + k] + bias[n] )
template <int ACT>
__global__ __launch_bounds__(256) void gemm_xwT(
    const float* __restrict__ X1, int ldx1,
    const float* __restrict__ X2, int ldx2, int ksplit,
    const float* __restrict__ W, int ldw, int woff,
    const float* __restrict__ bias,
    float* __restrict__ C, int ldc,
    int M, int N, int K)
{
  __shared__ float Xs[16][65];
  __shared__ float Ws[16][65];
  const int tid = threadIdx.x;
  const int tx = tid & 15, ty = tid >> 4;
  const int m0 = blockIdx.y * 64, n0 = blockIdx.x * 64;
  const int lrow = tid >> 2;
  const int kq4  = (tid & 3) * 4;
  float acc[4][4] = {};
  for (int k0 = 0; k0 < K; k0 += 16) {
    {
      const int m = m0 + lrow;
      #pragma unroll
      for (int j = 0; j < 4; ++j) {
        const int k = k0 + kq4 + j;
        float v = 0.f;
        if (m < M)
          v = (k < ksplit) ? X1[(size_t)m * ldx1 + k]
                           : X2[(size_t)m * ldx2 + (k - ksplit)];
        Xs[kq4 + j][lrow] = v;
      }
      const int n = n0 + lrow;
      #pragma unroll
      for (int j = 0; j < 4; ++j) {
        const int k = k0 + kq4 + j;
        Ws[kq4 + j][lrow] = (n < N) ? W[(size_t)n * ldw + woff + k] : 0.f;
      }
    }
    __syncthreads();
    #pragma unroll
    for (int kk = 0; kk < 16; ++kk) {
      float a[4], b[4];
      #pragma unroll
      for (int i = 0; i < 4; ++i) a[i] = Xs[kk][ty * 4 + i];
      #pragma unroll
      for (int j = 0; j < 4; ++j) b[j] = Ws[kk][tx * 4 + j];
      #pragma unroll
      for (int i = 0; i < 4; ++i)
        #pragma unroll
        for (int j = 0; j < 4; ++j)
          acc[i][j] += a[i] * b[j];
    }
    __syncthreads();
  }
  #pragma unroll
  for (int i = 0; i < 4; ++i) {
    const int m = m0 + ty * 4 + i;
    if (m >= M) continue;
    #pragma unroll
    for (int j = 0; j < 4; ++j) {
      const int n = n0 + tx * 4 + j;
      if (n >= N) continue;
      float v = acc[i][j] + bias[n];
      if (ACT == 1) v = eluf(v);
      if (ACT == 2) {
        if (n < 1024) C[(size_t)m * 1024 + n] = v;
        else          C[(size_t)m * 1024 + (n - 1024) + 1024 * 1024] = softplusf(v) + 0.1f;
      } else {
        C[(size_t)m * ldc + n] = v;
      }
    }
  }
}

extern "C" void kernel_launch(void* const* d_in, const int* in_sizes, int n_in,
                              void* d_out, int out_size, void* d_ws, size_t ws_size,
                              hipStream_t stream)
{
  const float* obs      = (const float*)d_in[0];
  const float* acts     = (const float*)d_in[1];
  const float* noise    = (const float*)d_in[2];
  const float* enc_w    = (const float*)d_in[3];
  const float* enc_b    = (const float*)d_in[4];
  const float* dec_w    = (const float*)d_in[5];
  const float* dec_b    = (const float*)d_in[6];
  const float* p_enc_w  = (const float*)d_in[7];
  const float* p_enc_b  = (const float*)d_in[8];
  const float* gru_wih  = (const float*)d_in[9];
  const float* gru_whh  = (const float*)d_in[10];
  const float* gru_b    = (const float*)d_in[11];
  const float* gru_bn   = (const float*)d_in[12];
  const float* p_dec1_w = (const float*)d_in[13];
  const float* p_dec1_b = (const float*)d_in[14];
  const float* p_dec2_w = (const float*)d_in[15];
  const float* p_dec2_b = (const float*)d_in[16];
  const float* q_enc_w  = (const float*)d_in[17];
  const float* q_enc_b  = (const float*)d_in[18];
  const float* q_dec_w  = (const float*)d_in[19];
  const float* q_dec_b  = (const float*)d_in[20];

  float* out   = (float*)d_out;
  float* stoch = out;                     // [1024,1024]
  float* det   = out + 1048576;           // [1024,2048]
  float* outs  = out + 3145728;           // [1024,1026]
  float* qmu   = out + 4196352;           // [1024,1024]
  float* qstd  = out + 5244928;           // [1024,1024]
  float* pmu   = out + 6293504;           // [1024,1024] (pstd adjacent)

  float* ws       = (float*)d_ws;
  float* pre_act  = ws;                          // 2,097,152 f
  float* pre_e    = ws + 2097152;                // 2,097,152 f
  float* emb      = ws + 4194304;                // 2,097,152 f
  float* xbuf     = ws + 6291456;                // 2048 f
  float* qbuf     = ws + 6293504;                // 2048 f
  unsigned* flags = (unsigned*)(ws + 6295552);   // 256 u32 packed (16B aligned)
  ushort_t* wpack = (ushort_t*)(ws + 6299648);
  ushort_t* wps_h = wpack;                       //  2,097,152 us
  ushort_t* wih_h = wps_h + 2097152;             // 12,582,912 us
  ushort_t* whh_h = wih_h + 12582912;            // 12,582,912 us
  ushort_t* wqe_h = whh_h + 12582912;            //  4,194,304 us
  ushort_t* wqd_h = wqe_h + 4194304;             //  4,194,304 us

  init_flags<<<dim3(1), dim3(256), 0, stream>>>(flags);

  // bf16 pack with chunk swizzle
  pack_swz<<<dim3(1024), dim3(256), 0, stream>>>(p_enc_w, (unsigned*)wps_h, 1088, 10, 1048576);
  pack_swz<<<dim3(1024), dim3(256), 0, stream>>>(gru_wih, (unsigned*)wih_h, 2048, 11, 6291456);
  pack_swz<<<dim3(1024), dim3(256), 0, stream>>>(gru_whh, (unsigned*)whh_h, 2048, 11, 6291456);
  pack_swz<<<dim3(1024), dim3(256), 0, stream>>>(q_enc_w, (unsigned*)wqe_h, 4096, 11, 2097152);
  pack_swz<<<dim3(1024), dim3(256), 0, stream>>>(q_dec_w, (unsigned*)wqd_h, 2048, 11, 2097152);

  dim3 blk(256);
  gemm_xwT<0><<<dim3(32, 16), blk, 0, stream>>>(
      acts, 64, acts, 64, 64, p_enc_w, 1088, 1024, p_enc_b, pre_act, 2048, 1024, 2048, 64);
  gemm_xwT<1><<<dim3(32, 16), blk, 0, stream>>>(
      obs, 1024, obs, 1024, 1024, enc_w, 1024, 0, enc_b, emb, 2048, 1024, 2048, 1024);
  gemm_xwT<0><<<dim3(32, 16), blk, 0, stream>>>(
      emb, 2048, emb, 2048, 2048, q_enc_w, 4096, 2048, q_enc_b, pre_e, 2048, 1024, 2048, 2048);

  rssm_seq<<<dim3(NWG), dim3(NTHR), 0, stream>>>(
      pre_act, pre_e, xbuf, qbuf, flags,
      wps_h, wih_h, whh_h, gru_b, gru_bn, wqe_h, wqd_h,
      q_dec_b, noise, stoch, det, qmu, qstd);

  gemm_xwT<1><<<dim3(32, 16), blk, 0, stream>>>(
      det, 2048, det, 2048, 2048, p_dec1_w, 2048, 0, p_dec1_b, emb, 2048, 1024, 2048, 2048);
  gemm_xwT<2><<<dim3(32, 16), blk, 0, stream>>>(
      emb, 2048, emb, 2048, 2048, p_dec2_w, 2048, 0, p_dec2_b, pmu, 1024, 1024, 2048, 2048);
  gemm_xwT<0><<<dim3(17, 16), blk, 0, stream>>>(
      stoch, 1024, det, 2048, 1024, dec_w, 3072, 0, dec_b, outs, 1026, 1024, 1026, 3072);
}

// Round 8
// 35571.054 us; speedup vs baseline: 1.3743x; 1.1296x over previous
//
#include <hip/hip_runtime.h>
#include <cstdint>
#include <cstddef>

#define T_STEPS 1024
#define S_DIM   1024
#define A_DIM   64
#define D_DIM   2048
#define H_DIM   2048
#define NWG     256
#define NTHR    512    // 8 waves per WG, 1 WG per CU (forced by 143KB LDS)

typedef unsigned short ushort_t;

__device__ __forceinline__ float eluf(float v)      { return v > 0.f ? v : expm1f(v); }
__device__ __forceinline__ float softplusf(float v) { return v > 20.f ? v : log1pf(expf(v)); }
__device__ __forceinline__ float sigmoidf_(float v) { return 1.f / (1.f + expf(-v)); }

__device__ __forceinline__ float wave_reduce(float v) {
  #pragma unroll
  for (int off = 32; off > 0; off >>= 1) v += __shfl_xor(v, off, 64);
  return v;
}

// unpack a u32 holding two bf16 (e0 = low half, e1 = high half)
__device__ __forceinline__ float2 bf2(unsigned u) {
  float2 r;
  r.x = __uint_as_float(u << 16);
  r.y = __uint_as_float(u & 0xffff0000u);
  return r;
}
__device__ __forceinline__ ushort_t f2bf_rne(float f) {
  unsigned u = __float_as_uint(f);
  u += 0x7fffu + ((u >> 16) & 1u);
  return (ushort_t)(u >> 16);
}

// ---- coherent (cross-XCD) accesses: bypass L1/L2, hit the coherence point.
__device__ __forceinline__ float4 ld_coh_f4(const float* p) {
  float4 v;
  asm volatile("global_load_dwordx4 %0, %1, off sc0 sc1\n\ts_waitcnt vmcnt(0)"
               : "=v"(v) : "v"(p) : "memory");
  return v;
}
__device__ __forceinline__ void st_coh_f1_fence(float* p, float v) {
  asm volatile("global_store_dword %0, %1, off sc0 sc1\n\ts_waitcnt vmcnt(0)"
               :: "v"(p), "v"(v) : "memory");
}

// pinned (volatile) weight load: cannot be rematerialized/sunk into the loop.
#define LD_PIN_U4(dst, addr) \
  asm volatile("global_load_dwordx4 %0, %1, off" : "=v"(dst) : "v"(addr))

__global__ void init_flags(unsigned* f) { f[threadIdx.x] = 0u; }

// Packed-flag grid barrier: 256 contiguous u32; lane l polls flags[4l..4l+3].
__device__ __forceinline__ void grid_bar(unsigned* flags, int bid, unsigned gen, int tid) {
  __syncthreads();
  if (tid == 0)
    asm volatile("global_store_dword %0, %1, off sc0 sc1"
                 :: "v"(flags + bid), "v"(gen) : "memory");
  if (tid < 64) {
    const unsigned* p = flags + tid * 4;
    bool done;
    do {
      uint4 f;
      asm volatile("global_load_dwordx4 %0, %1, off sc0 sc1\n\ts_waitcnt vmcnt(0)"
                   : "=v"(f) : "v"(p) : "memory");
      done = (f.x >= gen) && (f.y >= gen) && (f.z >= gen) && (f.w >= gen);
    } while (!__all(done));
  }
  __syncthreads();
}

// fp32 -> bf16 LINEAR pack (row layout preserved, u32 = 2 adjacent bf16)
__global__ __launch_bounds__(256) void pack_lin(
    const float* __restrict__ src, unsigned* __restrict__ dst,
    int src_ld, int lc /*log2 cols*/, size_t total_u32)
{
  for (size_t u = (size_t)blockIdx.x * 256 + threadIdx.x; u < total_u32;
       u += (size_t)gridDim.x * 256) {
    const size_t pos = u * 2;
    const size_t row = pos >> lc;
    const int    col = (int)(pos & (((size_t)1 << lc) - 1));
    const float2 v = *(const float2*)(src + row * src_ld + col);
    dst[u] = (unsigned)f2bf_rne(v.x) | ((unsigned)f2bf_rne(v.y) << 16);
  }
}

// fp32 -> bf16 pack with per-512-chunk column swizzle (for register-resident dots):
// dst pos (within row): chunk*512 + l*8 + p*2 + e  <-  src k: chunk*512 + p*128 + l*2 + e
__global__ __launch_bounds__(256) void pack_swz(
    const float* __restrict__ src, unsigned* __restrict__ dst,
    int src_ld, int lc /*log2 cols*/, size_t total2 /*u32 count*/)
{
  for (size_t u = (size_t)blockIdx.x * 256 + threadIdx.x; u < total2;
       u += (size_t)gridDim.x * 256) {
    const size_t pos = u * 2;
    const size_t row = pos >> lc;
    const int pcol  = (int)(pos & (((size_t)1 << lc) - 1));
    const int chunk = pcol >> 9;
    const int off   = pcol & 511;
    const int l     = off >> 3;
    const int p     = (off >> 1) & 3;
    const float2 v  = *(const float2*)(src + row * src_ld + chunk * 512 + p * 128 + l * 2);
    dst[u] = (unsigned)f2bf_rne(v.x) | ((unsigned)f2bf_rne(v.y) << 16);
  }
}

// dot of one swizzled 512-chunk (uint4 = 8 bf16) against LDS chunk
__device__ __forceinline__ float chunk_dot(const uint4 w, const float* vchunk, int lane) {
  float acc = 0.f; float2 p, a;
  a = *(const float2*)(vchunk + lane * 2 +   0); p = bf2(w.x); acc += p.x*a.x + p.y*a.y;
  a = *(const float2*)(vchunk + lane * 2 + 128); p = bf2(w.y); acc += p.x*a.x + p.y*a.y;
  a = *(const float2*)(vchunk + lane * 2 + 256); p = bf2(w.z); acc += p.x*a.x + p.y*a.y;
  a = *(const float2*)(vchunk + lane * 2 + 384); p = bf2(w.w); acc += p.x*a.x + p.y*a.y;
  return acc;
}

__global__ __launch_bounds__(NTHR) void rssm_seq(
    const float* __restrict__ pre_act, const float* __restrict__ pre_e,
    float* __restrict__ xbuf, float* __restrict__ qbuf, unsigned* __restrict__ flags,
    const unsigned* __restrict__ wps_lin,   // [2048][512 u32]  (1024 bf16 per row)
    const unsigned* __restrict__ wih_lin,   // [6144][1024 u32] (2048 bf16 per row)
    const ushort_t* __restrict__ whh_swz,   // [6144][2048] swizzled
    const ushort_t* __restrict__ wqe_swz,   // [2048][2048] swizzled
    const ushort_t* __restrict__ wqd_swz,   // [2048][2048] swizzled
    const float* __restrict__ gru_b, const float* __restrict__ gru_bn,
    const float* __restrict__ q_dec_b, const float* __restrict__ noise,
    float* __restrict__ stoch_out, float* __restrict__ det_out,
    float* __restrict__ qmu_out, float* __restrict__ qstd_out)
{
  // ---- 143,392 B static LDS: forces 1 WG/CU -> RA budget 256 VGPR/wave ----
  __shared__ float    xs[2048];          //  8 KB  x vector
  __shared__ float    ds[2048];          //  8 KB  det_prev -> det_t (persists)
  __shared__ float    qs[2048];          //  8 KB  q vector
  __shared__ float    sp[1024];          //  4 KB  stoch_prev
  __shared__ float    part4[8];
  __shared__ unsigned wps_l[8 * 512];    // 16 KB  stage-1 weights (8 rows x 1024 bf16)
  __shared__ unsigned wih_l[24 * 1024];  // 96 KB  GRU ih weights (3 gates x 8 rows x 2048 bf16)

  const int tid  = threadIdx.x;
  const int wv   = tid >> 6;          // 0..7 — this wave's row
  const int lane = tid & 63;
  const int bid  = blockIdx.x;
  const int r0   = bid * 8;
  unsigned gen = 0;

  // ---------------- one-time LDS weight fill (linear layout, coalesced) ----------------
  #pragma unroll
  for (int i = 0; i < 8; ++i) {
    const int idx = i * NTHR + tid;            // 0..4095
    const int row = idx >> 9, u = idx & 511;
    wps_l[idx] = wps_lin[((size_t)(r0 + row) << 9) | u];
  }
  #pragma unroll
  for (int i = 0; i < 48; ++i) {
    const int idx = i * NTHR + tid;            // 0..24575
    const int gr = idx >> 10, u = idx & 1023;  // gr: 0..23
    const int g = gr >> 3, rr = gr & 7;
    wih_l[idx] = wih_lin[((size_t)(g * 2048 + r0 + rr) << 10) | u];
  }

  // ---------------- pinned register weights (volatile loads, swizzled layout) ----------------
  uint4 w2h[12];   // GRU hh: 3 gates x 4 chunks for row r0+wv
  uint4 w3[4];     // wqe row r0+wv, 4 chunks
  uint4 w4[4];     // wqd dot wv, 4 chunks
  {
    const size_t i = (size_t)(r0 + wv);
    #pragma unroll
    for (int g = 0; g < 3; ++g) {
      const uint4* wr = (const uint4*)(whh_swz + (i + (size_t)g * 2048) * 2048);
      #pragma unroll
      for (int c = 0; c < 4; ++c) LD_PIN_U4(w2h[g * 4 + c], wr + c * 64 + lane);
    }
    const uint4* we = (const uint4*)(wqe_swz + i * 2048);
    #pragma unroll
    for (int c = 0; c < 4; ++c) LD_PIN_U4(w3[c], we + c * 64 + lane);
    const int jg = bid * 4 + (wv & 3), sel = wv >> 2;
    const uint4* wd = (const uint4*)(wqd_swz + (size_t)(jg + sel * 1024) * 2048);
    #pragma unroll
    for (int c = 0; c < 4; ++c) LD_PIN_U4(w4[c], wd + c * 64 + lane);
    asm volatile("s_waitcnt vmcnt(0)" ::: "memory");
  }

  // per-wave constants (lane 0 only, used in lane-0 epilogues)
  float gb_r = 0.f, gb_z = 0.f, gb_n = 0.f, gbn = 0.f;
  if (lane == 0) {
    gb_r = gru_b[r0 + wv];
    gb_z = gru_b[r0 + wv + 2048];
    gb_n = gru_b[r0 + wv + 4096];
    gbn  = gru_bn[r0 + wv];
  }
  float qdb_m = 0.f, qdb_s = 0.f;
  if (tid < 4) {
    qdb_m = q_dec_b[bid * 4 + tid];
    qdb_s = q_dec_b[bid * 4 + tid + 1024];
  }

  // zero initial state (sp/ds persist; overwritten by staging at t>0)
  if (tid < 256) ((float4*)sp)[tid] = float4{0.f, 0.f, 0.f, 0.f};
  ((float4*)ds)[tid] = float4{0.f, 0.f, 0.f, 0.f};
  __syncthreads();

  for (int t = 0; t < T_STEPS; ++t) {
    // per-step small loads
    float pa = 0.f, pe = 0.f, nz = 0.f;
    if (lane == 0) {
      pa = pre_act[(size_t)t * D_DIM + r0 + wv];
      pe = pre_e  [(size_t)t * H_DIM + r0 + wv];
    }
    if (tid < 4) nz = noise[(size_t)t * S_DIM + bid * 4 + tid];

    // stage stoch_prev
    if (t > 0 && tid < 256)
      ((float4*)sp)[tid] = ld_coh_f4(stoch_out + (size_t)(t - 1) * S_DIM + tid * 4);
    __syncthreads();

    // ======== stage 1: x = elu(Wps @ stoch_prev + pre_act[t]) — weights in LDS ========
    {
      const unsigned* wrow = wps_l + (wv << 9);
      float acc = 0.f;
      #pragma unroll
      for (int c = 0; c < 2; ++c)
        #pragma unroll
        for (int p = 0; p < 4; ++p) {
          const float2 a = *(const float2*)(sp + c * 512 + p * 128 + lane * 2);
          const float2 w = bf2(wrow[c * 256 + p * 64 + lane]);
          acc += w.x * a.x + w.y * a.y;
        }
      acc = wave_reduce(acc);
      if (lane == 0) st_coh_f1_fence(xbuf + r0 + wv, eluf(acc + pa));
    }
    grid_bar(flags, bid, ++gen, tid);

    // ======== stage 2: GRU -> det[t] — ih from LDS, hh from pinned regs ========
    ((float4*)xs)[tid] = ld_coh_f4(xbuf + tid * 4);
    __syncthreads();
    {
      const unsigned* wg0 = wih_l + wv * 1024;
      const unsigned* wg1 = wg0 + 8192;
      const unsigned* wg2 = wg1 + 8192;
      float a0 = 0.f, a1 = 0.f, a2 = 0.f, h0 = 0.f, h1 = 0.f, h2 = 0.f;
      #pragma unroll
      for (int c = 0; c < 4; ++c) {
        #pragma unroll
        for (int p = 0; p < 4; ++p) {
          const int kb = c * 512 + p * 128 + lane * 2;
          const float2 xv = *(const float2*)(xs + kb);
          const float2 dv = *(const float2*)(ds + kb);
          const int wi = c * 256 + p * 64 + lane;
          float2 w;
          w = bf2(wg0[wi]); a0 += w.x * xv.x + w.y * xv.y;
          w = bf2(wg1[wi]); a1 += w.x * xv.x + w.y * xv.y;
          w = bf2(wg2[wi]); a2 += w.x * xv.x + w.y * xv.y;
          const unsigned u0 = (p == 0) ? w2h[c].x     : (p == 1) ? w2h[c].y     : (p == 2) ? w2h[c].z     : w2h[c].w;
          const unsigned u1 = (p == 0) ? w2h[4 + c].x : (p == 1) ? w2h[4 + c].y : (p == 2) ? w2h[4 + c].z : w2h[4 + c].w;
          const unsigned u2 = (p == 0) ? w2h[8 + c].x : (p == 1) ? w2h[8 + c].y : (p == 2) ? w2h[8 + c].z : w2h[8 + c].w;
          w = bf2(u0); h0 += w.x * dv.x + w.y * dv.y;
          w = bf2(u1); h1 += w.x * dv.x + w.y * dv.y;
          w = bf2(u2); h2 += w.x * dv.x + w.y * dv.y;
        }
      }
      a0 = wave_reduce(a0); a1 = wave_reduce(a1); a2 = wave_reduce(a2);
      h0 = wave_reduce(h0); h1 = wave_reduce(h1); h2 = wave_reduce(h2);
      if (lane == 0) {
        const float r_ = sigmoidf_(a0 + gb_r + h0);
        const float z_ = sigmoidf_(a1 + gb_z + h1);
        const float n_ = tanhf(a2 + gb_n + r_ * (h2 + gbn));
        st_coh_f1_fence(det_out + (size_t)t * D_DIM + r0 + wv,
                        n_ + z_ * (ds[r0 + wv] - n_));
      }
    }
    grid_bar(flags, bid, ++gen, tid);

    // ======== stage 3: q = elu(Wqe @ det_t + pre_e[t]) — weights in regs ========
    ((float4*)ds)[tid] = ld_coh_f4(det_out + (size_t)t * D_DIM + tid * 4);
    __syncthreads();
    {
      float acc = 0.f;
      #pragma unroll
      for (int c = 0; c < 4; ++c) acc += chunk_dot(w3[c], ds + c * 512, lane);
      acc = wave_reduce(acc);
      if (lane == 0) st_coh_f1_fence(qbuf + r0 + wv, eluf(acc + pe));
    }
    grid_bar(flags, bid, ++gen, tid);

    // ======== stage 4: posterior head + sample — weights in regs ========
    ((float4*)qs)[tid] = ld_coh_f4(qbuf + tid * 4);
    __syncthreads();
    {
      float acc = 0.f;
      #pragma unroll
      for (int c = 0; c < 4; ++c) acc += chunk_dot(w4[c], qs + c * 512, lane);
      acc = wave_reduce(acc);
      if (lane == 0) part4[wv] = acc;
    }
    __syncthreads();
    if (tid < 4) {
      const int j = bid * 4 + tid;
      const float qm  = part4[tid] + qdb_m;
      const float qsd = softplusf(part4[tid + 4] + qdb_s) + 0.1f;
      qmu_out [(size_t)t * S_DIM + j] = qm;
      qstd_out[(size_t)t * S_DIM + j] = qsd;
      st_coh_f1_fence(stoch_out + (size_t)t * S_DIM + j, qm + qsd * nz);
    }
    grid_bar(flags, bid, ++gen, tid);
  }
}

// C[m,n] = act( sum_k Xc[m,k] * W[n*ldw + woff + k] + bias[n] )
template <int ACT>
__global__ __launch_bounds__(256) void gemm_xwT(
    const float* __restrict__ X1, int ldx1,
    const float* __restrict__ X2, int ldx2, int ksplit,
    const float* __restrict__ W, int ldw, int woff,
    const float* __restrict__ bias,
    float* __restrict__ C, int ldc,
    int M, int N, int K)
{
  __shared__ float Xs[16][65];
  __shared__ float Ws[16][65];
  const int tid = threadIdx.x;
  const int tx = tid & 15, ty = tid >> 4;
  const int m0 = blockIdx.y * 64, n0 = blockIdx.x * 64;
  const int lrow = tid >> 2;
  const int kq4  = (tid & 3) * 4;
  float acc[4][4] = {};
  for (int k0 = 0; k0 < K; k0 += 16) {
    {
      const int m = m0 + lrow;
      #pragma unroll
      for (int j = 0; j < 4; ++j) {
        const int k = k0 + kq4 + j;
        float v = 0.f;
        if (m < M)
          v = (k < ksplit) ? X1[(size_t)m * ldx1 + k]
                           : X2[(size_t)m * ldx2 + (k - ksplit)];
        Xs[kq4 + j][lrow] = v;
      }
      const int n = n0 + lrow;
      #pragma unroll
      for (int j = 0; j < 4; ++j) {
        const int k = k0 + kq4 + j;
        Ws[kq4 + j][lrow] = (n < N) ? W[(size_t)n * ldw + woff + k] : 0.f;
      }
    }
    __syncthreads();
    #pragma unroll
    for (int kk = 0; kk < 16; ++kk) {
      float a[4], b[4];
      #pragma unroll
      for (int i = 0; i < 4; ++i) a[i] = Xs[kk][ty * 4 + i];
      #pragma unroll
      for (int j = 0; j < 4; ++j) b[j] = Ws[kk][tx * 4 + j];
      #pragma unroll
      for (int i = 0; i < 4; ++i)
        #pragma unroll
        for (int j = 0; j < 4; ++j)
          acc[i][j] += a[i] * b[j];
    }
    __syncthreads();
  }
  #pragma unroll
  for (int i = 0; i < 4; ++i) {
    const int m = m0 + ty * 4 + i;
    if (m >= M) continue;
    #pragma unroll
    for (int j = 0; j < 4; ++j) {
      const int n = n0 + tx * 4 + j;
      if (n >= N) continue;
      float v = acc[i][j] + bias[n];
      if (ACT == 1) v = eluf(v);
      if (ACT == 2) {
        if (n < 1024) C[(size_t)m * 1024 + n] = v;
        else          C[(size_t)m * 1024 + (n - 1024) + 1024 * 1024] = softplusf(v) + 0.1f;
      } else {
        C[(size_t)m * ldc + n] = v;
      }
    }
  }
}

extern "C" void kernel_launch(void* const* d_in, const int* in_sizes, int n_in,
                              void* d_out, int out_size, void* d_ws, size_t ws_size,
                              hipStream_t stream)
{
  const float* obs      = (const float*)d_in[0];
  const float* acts     = (const float*)d_in[1];
  const float* noise    = (const float*)d_in[2];
  const float* enc_w    = (const float*)d_in[3];
  const float* enc_b    = (const float*)d_in[4];
  const float* dec_w    = (const float*)d_in[5];
  const float* dec_b    = (const float*)d_in[6];
  const float* p_enc_w  = (const float*)d_in[7];
  const float* p_enc_b  = (const float*)d_in[8];
  const float* gru_wih  = (const float*)d_in[9];
  const float* gru_whh  = (const float*)d_in[10];
  const float* gru_b    = (const float*)d_in[11];
  const float* gru_bn   = (const float*)d_in[12];
  const float* p_dec1_w = (const float*)d_in[13];
  const float* p_dec1_b = (const float*)d_in[14];
  const float* p_dec2_w = (const float*)d_in[15];
  const float* p_dec2_b = (const float*)d_in[16];
  const float* q_enc_w  = (const float*)d_in[17];
  const float* q_enc_b  = (const float*)d_in[18];
  const float* q_dec_w  = (const float*)d_in[19];
  const float* q_dec_b  = (const float*)d_in[20];

  float* out   = (float*)d_out;
  float* stoch = out;                     // [1024,1024]
  float* det   = out + 1048576;           // [1024,2048]
  float* outs  = out + 3145728;           // [1024,1026]
  float* qmu   = out + 4196352;           // [1024,1024]
  float* qstd  = out + 5244928;           // [1024,1024]
  float* pmu   = out + 6293504;           // [1024,1024] (pstd adjacent)

  float* ws       = (float*)d_ws;
  float* pre_act  = ws;                          // 2,097,152 f
  float* pre_e    = ws + 2097152;                // 2,097,152 f
  float* emb      = ws + 4194304;                // 2,097,152 f
  float* xbuf     = ws + 6291456;                // 2048 f
  float* qbuf     = ws + 6293504;                // 2048 f
  unsigned* flags = (unsigned*)(ws + 6295552);   // 256 u32 packed
  ushort_t* wpack = (ushort_t*)(ws + 6299648);
  // (same 71.3 MB pack region as verified rounds)
  ushort_t* wps_lin = wpack;                     //  2,097,152 us (LDS-dest, linear)
  ushort_t* wih_lin = wps_lin + 2097152;         // 12,582,912 us (LDS-dest, linear)
  ushort_t* whh_swz = wih_lin + 12582912;        // 12,582,912 us (reg-dest, swz)
  ushort_t* wqe_swz = whh_swz + 12582912;        //  4,194,304 us (reg-dest, swz)
  ushort_t* wqd_swz = wqe_swz + 4194304;         //  4,194,304 us (reg-dest, swz)

  init_flags<<<dim3(1), dim3(256), 0, stream>>>(flags);

  // packs: linear for LDS-resident weights, swizzled for register-resident
  pack_lin<<<dim3(1024), dim3(256), 0, stream>>>(p_enc_w, (unsigned*)wps_lin, 1088, 10, 1048576);
  pack_lin<<<dim3(1024), dim3(256), 0, stream>>>(gru_wih, (unsigned*)wih_lin, 2048, 11, 6291456);
  pack_swz<<<dim3(1024), dim3(256), 0, stream>>>(gru_whh, (unsigned*)whh_swz, 2048, 11, 6291456);
  pack_swz<<<dim3(1024), dim3(256), 0, stream>>>(q_enc_w, (unsigned*)wqe_swz, 4096, 11, 2097152);
  pack_swz<<<dim3(1024), dim3(256), 0, stream>>>(q_dec_w, (unsigned*)wqd_swz, 2048, 11, 2097152);

  dim3 blk(256);
  gemm_xwT<0><<<dim3(32, 16), blk, 0, stream>>>(
      acts, 64, acts, 64, 64, p_enc_w, 1088, 1024, p_enc_b, pre_act, 2048, 1024, 2048, 64);
  gemm_xwT<1><<<dim3(32, 16), blk, 0, stream>>>(
      obs, 1024, obs, 1024, 1024, enc_w, 1024, 0, enc_b, emb, 2048, 1024, 2048, 1024);
  gemm_xwT<0><<<dim3(32, 16), blk, 0, stream>>>(
      emb, 2048, emb, 2048, 2048, q_enc_w, 4096, 2048, q_enc_b, pre_e, 2048, 1024, 2048, 2048);

  rssm_seq<<<dim3(NWG), dim3(NTHR), 0, stream>>>(
      pre_act, pre_e, xbuf, qbuf, flags,
      (const unsigned*)wps_lin, (const unsigned*)wih_lin,
      whh_swz, wqe_swz, wqd_swz,
      gru_b, gru_bn, q_dec_b, noise, stoch, det, qmu, qstd);

  gemm_xwT<1><<<dim3(32, 16), blk, 0, stream>>>(
      det, 2048, det, 2048, 2048, p_dec1_w, 2048, 0, p_dec1_b, emb, 2048, 1024, 2048, 2048);
  gemm_xwT<2><<<dim3(32, 16), blk, 0, stream>>>(
      emb, 2048, emb, 2048, 2048, p_dec2_w, 2048, 0, p_dec2_b, pmu, 1024, 1024, 2048, 2048);
  gemm_xwT<0><<<dim3(17, 16), blk, 0, stream>>>(
      stoch, 1024, det, 2048, 1024, dec_w, 3072, 0, dec_b, outs, 1026, 1024, 1026, 3072);
}